// Round 3
// baseline (98.872 us; speedup 1.0000x reference)
//
#include <hip/hip_runtime.h>
#include <math.h>

#define NPTS 2048
#define KDIM 400
#define NBLK 256          // 128 FF + 128 kval; also phase-2 grid (256*512 = 64*2048)

// Fused: phase 1 = FF (blocks 0..127, 2 per batch row) + kval (blocks 128..255,
// 16 points x 16 slots x 2 fields = 512 threads); device barrier; phase 2 = field
// contraction, one thread per (b,n).
__global__ __launch_bounds__(512) void k_fused(
    const float* __restrict__ weights, const float* __restrict__ grid,
    const float* __restrict__ ff_w1, const float* __restrict__ ff_b1,
    const float* __restrict__ ff_w2, const float* __restrict__ ff_b2,
    const float* __restrict__ ff_w3, const float* __restrict__ ff_b3,
    const float* __restrict__ k_w1, const float* __restrict__ k_b1,
    const float* __restrict__ k_w2, const float* __restrict__ k_b2,
    const float* __restrict__ k_w3, const float* __restrict__ k_b3,
    float* __restrict__ integ, float* __restrict__ kv0,
    float* __restrict__ kv1, int* __restrict__ kidx,
    unsigned int* __restrict__ bar, float2* __restrict__ out)
{
    __shared__ float S[2048];      // phase-1 FF: 1976 floats; kval: 1002; phase-2: 400
    const int t = threadIdx.x;
    const int bid = blockIdx.x;

    if (bid < 128) {
        // ---- FeedForward: block pair (b, half), split-K layers ----
        const int b    = bid >> 1;
        const int half = bid & 1;
        float* wrow = S;            // 256
        float* h1   = S + 256;      // 120
        float* h2   = S + 376;      // 240
        float* p1   = S + 616;      // 4*120
        float* p2   = S + 1096;     // 2*240
        float* p3   = S + 1576;     // 2*200

        if (t < 256) wrow[t] = weights[b * 256 + t];
        __syncthreads();

        if (t < 480) {              // layer 1: 120 outs, 4-way split-K (64 each)
            const int seg = t / 120;
            const int o   = t - seg * 120;
            float s = (seg == 0) ? ff_b1[o] : 0.f;
            const int i0 = seg * 64;
            #pragma unroll 16
            for (int i = 0; i < 64; ++i)
                s = fmaf(wrow[i0 + i], ff_w1[(i0 + i) * 120 + o], s);
            p1[seg * 120 + o] = s;
        }
        __syncthreads();
        if (t < 120) h1[t] = tanhf(p1[t] + p1[120 + t] + p1[240 + t] + p1[360 + t]);
        __syncthreads();

        if (t < 480) {              // layer 2: 240 outs, 2-way split-K (60 each)
            const int seg = t / 240;
            const int o   = t - seg * 240;
            float s = (seg == 0) ? ff_b2[o] : 0.f;
            const int i0 = seg * 60;
            #pragma unroll 15
            for (int i = 0; i < 60; ++i)
                s = fmaf(h1[i0 + i], ff_w2[(i0 + i) * 240 + o], s);
            p2[seg * 240 + o] = s;
        }
        __syncthreads();
        if (t < 240) h2[t] = tanhf(p2[t] + p2[240 + t]);
        __syncthreads();

        if (t < 400) {              // layer 3: this block's 200 outs, 2-way split-K
            const int seg = t / 200;
            const int o   = t - seg * 200;
            const int oc  = half * 200 + o;
            float s = (seg == 0) ? ff_b3[oc] : 0.f;
            const int i0 = seg * 120;
            #pragma unroll 15
            for (int i = 0; i < 120; ++i)
                s = fmaf(h2[i0 + i], ff_w3[(i0 + i) * 400 + oc], s);
            p3[seg * 200 + o] = s;
        }
        __syncthreads();
        if (t < 200) integ[b * 400 + half * 200 + t] = p3[t] + p3[200 + t];
    } else {
        // ---- sparse kernel-MLP eval: thread = (n, slot, f) ----
        float* sw1 = S;             // 80
        float* sb1 = S + 80;        // 40
        float* sw2 = S + 120;       // 800
        float* sb2 = S + 920;       // 40
        float* sw3 = S + 960;       // 40
        float* sb3 = S + 1000;      // 2
        for (int i = t; i < 80;  i += 512) sw1[i] = k_w1[i];
        for (int i = t; i < 800; i += 512) sw2[i] = k_w2[i];
        if (t < 40) { sb1[t] = k_b1[t]; sb2[t] = k_b2[t]; sw3[t] = k_w3[t]; }
        if (t < 2)  sb3[t] = k_b3[t];
        __syncthreads();

        const int pid  = bid - 128;       // 0..127, 16 points each
        const int f    = t >> 8;          // 0/1
        const int idx  = t & 255;
        const int slot = idx >> 4;        // 0..15 -> 4x4 window
        const int n    = pid * 16 + (idx & 15);
        const float2 g2 = ((const float2*)grid)[n];
        const float x = g2.x, y = g2.y;
        const int ilx = (int)ceilf((x - 0.15f) * 20.0f - 0.01f);
        const int ily = (int)ceilf((y - 0.15f) * 20.0f - 0.01f);
        const int ix = ilx + (slot >> 2);
        const int iy = ily + (slot & 3);

        float kv = 0.f;
        int k = 0;
        if (ix >= 0 && ix < 20 && iy >= 0 && iy < 20) {
            // replicate reference f32 arithmetic exactly (no fp-contract)
            const float gx = __fmul_rn((float)ix, 0.05f);
            const float gy = __fmul_rn((float)iy, 0.05f);
            const float lx = __fsub_rn(x, gx);
            const float ly = __fsub_rn(y, gy);
            if (lx >= 0.f && lx <= 0.15f && ly >= 0.f && ly <= 0.15f) {
                k = ix * 20 + iy;
                float hv[20];
                #pragma unroll
                for (int hh = 0; hh < 20; ++hh)
                    hv[hh] = fmaxf(0.f,
                        fmaf(lx, sw1[f * 40 + hh],
                        fmaf(ly, sw1[f * 40 + 20 + hh], sb1[f * 20 + hh])));
                float o = sb3[f];
                #pragma unroll
                for (int g = 0; g < 20; ++g) {
                    float s = sb2[f * 20 + g];
                    #pragma unroll
                    for (int hh = 0; hh < 20; ++hh)
                        s = fmaf(hv[hh], sw2[f * 400 + hh * 20 + g], s);
                    o = fmaf(fmaxf(0.f, s), sw3[f * 20 + g], o);
                }
                kv = o;
            }
        }
        (f ? kv1 : kv0)[slot * NPTS + n] = kv;
        if (f == 0) kidx[slot * NPTS + n] = k;   // k=0 with kv=0 is harmless
    }

    // ---- device-scope barrier (counter zeroed by memsetAsync each call) ----
    __threadfence();
    __syncthreads();
    if (t == 0) {
        __hip_atomic_fetch_add(bar, 1u, __ATOMIC_RELEASE, __HIP_MEMORY_SCOPE_AGENT);
        while (__hip_atomic_load(bar, __ATOMIC_ACQUIRE, __HIP_MEMORY_SCOPE_AGENT)
               < (unsigned)NBLK)
            __builtin_amdgcn_s_sleep(2);
    }
    __syncthreads();

    // ---- phase 2: fields[b,n,f] = sigmoid(sum_j kv[f,n,j] * integ[b, kidx[n,j]])
    const int tid = bid * 512 + t;        // == b*2048 + n
    const int b = tid >> 11;
    const int n = tid & (NPTS - 1);
    float* srow = S;                      // this block's integ row (same b for all t)
    for (int i = t; i < KDIM; i += 512) srow[i] = integ[b * KDIM + i];
    __syncthreads();

    float a0 = 0.f, a1 = 0.f;
    #pragma unroll
    for (int j = 0; j < 16; ++j) {
        const int k = kidx[j * NPTS + n];
        const float w = srow[k];
        a0 = fmaf(kv0[j * NPTS + n], w, a0);
        a1 = fmaf(kv1[j * NPTS + n], w, a1);
    }
    out[tid] = make_float2(1.f / (1.f + __expf(-a0)),
                           1.f / (1.f + __expf(-a1)));
}

extern "C" void kernel_launch(void* const* d_in, const int* in_sizes, int n_in,
                              void* d_out, int out_size, void* d_ws, size_t ws_size,
                              hipStream_t stream) {
    const float* weights = (const float*)d_in[0];
    const float* grid    = (const float*)d_in[1];
    const float* ff_w1   = (const float*)d_in[2];
    const float* ff_b1   = (const float*)d_in[3];
    const float* ff_w2   = (const float*)d_in[4];
    const float* ff_b2   = (const float*)d_in[5];
    const float* ff_w3   = (const float*)d_in[6];
    const float* ff_b3   = (const float*)d_in[7];
    const float* k_w1    = (const float*)d_in[8];
    const float* k_b1    = (const float*)d_in[9];
    const float* k_w2    = (const float*)d_in[10];
    const float* k_b2    = (const float*)d_in[11];
    const float* k_w3    = (const float*)d_in[12];
    const float* k_b3    = (const float*)d_in[13];

    float* integ = (float*)d_ws;                 // 64*400
    float* kv0   = integ + 64 * KDIM;            // 16*2048
    float* kv1   = kv0 + 16 * NPTS;              // 16*2048
    int*   kidx  = (int*)(kv1 + 16 * NPTS);      // 16*2048
    unsigned int* bar = (unsigned int*)(kidx + 16 * NPTS);

    hipMemsetAsync(bar, 0, sizeof(unsigned int), stream);

    k_fused<<<NBLK, 512, 0, stream>>>(
        weights, grid, ff_w1, ff_b1, ff_w2, ff_b2, ff_w3, ff_b3,
        k_w1, k_b1, k_w2, k_b2, k_w3, k_b3,
        integ, kv0, kv1, kidx, bar, (float2*)d_out);
}

// Round 4
// 30.225 us; speedup vs baseline: 3.2712x; 3.2712x over previous
//
#include <hip/hip_runtime.h>
#include <math.h>

#define NPTS 2048
#define KDIM 400
#define NBLK 256          // 128 FF + 128 kval; also phase-2 grid (256*512 = 64*2048)

// Fused: phase 1 = FF (blocks 0..127, 2 per batch row) + kval (blocks 128..255,
// 16 points x 16 slots x 2 fields = 512 threads); device barrier (relaxed-poll,
// single release/acquire fences); phase 2 = field contraction, 1 thread/(b,n).
__global__ __launch_bounds__(512) void k_fused(
    const float* __restrict__ weights, const float* __restrict__ grid,
    const float* __restrict__ ff_w1, const float* __restrict__ ff_b1,
    const float* __restrict__ ff_w2, const float* __restrict__ ff_b2,
    const float* __restrict__ ff_w3, const float* __restrict__ ff_b3,
    const float* __restrict__ k_w1, const float* __restrict__ k_b1,
    const float* __restrict__ k_w2, const float* __restrict__ k_b2,
    const float* __restrict__ k_w3, const float* __restrict__ k_b3,
    float* __restrict__ integ, float* __restrict__ kv0,
    float* __restrict__ kv1, int* __restrict__ kidx,
    unsigned int* __restrict__ bar, float2* __restrict__ out)
{
    __shared__ float S[2048];      // phase-1 FF: 1976 floats; kval: 1002; phase-2: 400
    const int t = threadIdx.x;
    const int bid = blockIdx.x;

    if (bid < 128) {
        // ---- FeedForward: block pair (b, half), split-K layers ----
        const int b    = bid >> 1;
        const int half = bid & 1;
        float* wrow = S;            // 256
        float* h1   = S + 256;      // 120
        float* h2   = S + 376;      // 240
        float* p1   = S + 616;      // 4*120
        float* p2   = S + 1096;     // 2*240
        float* p3   = S + 1576;     // 2*200

        if (t < 256) wrow[t] = weights[b * 256 + t];
        __syncthreads();

        if (t < 480) {              // layer 1: 120 outs, 4-way split-K (64 each)
            const int seg = t / 120;
            const int o   = t - seg * 120;
            float s = (seg == 0) ? ff_b1[o] : 0.f;
            const int i0 = seg * 64;
            #pragma unroll 16
            for (int i = 0; i < 64; ++i)
                s = fmaf(wrow[i0 + i], ff_w1[(i0 + i) * 120 + o], s);
            p1[seg * 120 + o] = s;
        }
        __syncthreads();
        if (t < 120) h1[t] = tanhf(p1[t] + p1[120 + t] + p1[240 + t] + p1[360 + t]);
        __syncthreads();

        if (t < 480) {              // layer 2: 240 outs, 2-way split-K (60 each)
            const int seg = t / 240;
            const int o   = t - seg * 240;
            float s = (seg == 0) ? ff_b2[o] : 0.f;
            const int i0 = seg * 60;
            #pragma unroll 15
            for (int i = 0; i < 60; ++i)
                s = fmaf(h1[i0 + i], ff_w2[(i0 + i) * 240 + o], s);
            p2[seg * 240 + o] = s;
        }
        __syncthreads();
        if (t < 240) h2[t] = tanhf(p2[t] + p2[240 + t]);
        __syncthreads();

        if (t < 400) {              // layer 3: this block's 200 outs, 2-way split-K
            const int seg = t / 200;
            const int o   = t - seg * 200;
            const int oc  = half * 200 + o;
            float s = (seg == 0) ? ff_b3[oc] : 0.f;
            const int i0 = seg * 120;
            #pragma unroll 15
            for (int i = 0; i < 120; ++i)
                s = fmaf(h2[i0 + i], ff_w3[(i0 + i) * 400 + oc], s);
            p3[seg * 200 + o] = s;
        }
        __syncthreads();
        if (t < 200) integ[b * 400 + half * 200 + t] = p3[t] + p3[200 + t];
    } else {
        // ---- sparse kernel-MLP eval: thread = (n, slot, f) ----
        float* sw1 = S;             // 80
        float* sb1 = S + 80;        // 40
        float* sw2 = S + 120;       // 800
        float* sb2 = S + 920;       // 40
        float* sw3 = S + 960;      // 40
        float* sb3 = S + 1000;     // 2
        for (int i = t; i < 80;  i += 512) sw1[i] = k_w1[i];
        for (int i = t; i < 800; i += 512) sw2[i] = k_w2[i];
        if (t < 40) { sb1[t] = k_b1[t]; sb2[t] = k_b2[t]; sw3[t] = k_w3[t]; }
        if (t < 2)  sb3[t] = k_b3[t];
        __syncthreads();

        const int pid  = bid - 128;       // 0..127, 16 points each
        const int f    = t >> 8;          // 0/1
        const int idx  = t & 255;
        const int slot = idx >> 4;        // 0..15 -> 4x4 window
        const int n    = pid * 16 + (idx & 15);
        const float2 g2 = ((const float2*)grid)[n];
        const float x = g2.x, y = g2.y;
        const int ilx = (int)ceilf((x - 0.15f) * 20.0f - 0.01f);
        const int ily = (int)ceilf((y - 0.15f) * 20.0f - 0.01f);
        const int ix = ilx + (slot >> 2);
        const int iy = ily + (slot & 3);

        float kv = 0.f;
        int k = 0;
        if (ix >= 0 && ix < 20 && iy >= 0 && iy < 20) {
            // replicate reference f32 arithmetic exactly (no fp-contract)
            const float gx = __fmul_rn((float)ix, 0.05f);
            const float gy = __fmul_rn((float)iy, 0.05f);
            const float lx = __fsub_rn(x, gx);
            const float ly = __fsub_rn(y, gy);
            if (lx >= 0.f && lx <= 0.15f && ly >= 0.f && ly <= 0.15f) {
                k = ix * 20 + iy;
                float hv[20];
                #pragma unroll
                for (int hh = 0; hh < 20; ++hh)
                    hv[hh] = fmaxf(0.f,
                        fmaf(lx, sw1[f * 40 + hh],
                        fmaf(ly, sw1[f * 40 + 20 + hh], sb1[f * 20 + hh])));
                float o = sb3[f];
                #pragma unroll
                for (int g = 0; g < 20; ++g) {
                    float s = sb2[f * 20 + g];
                    #pragma unroll
                    for (int hh = 0; hh < 20; ++hh)
                        s = fmaf(hv[hh], sw2[f * 400 + hh * 20 + g], s);
                    o = fmaf(fmaxf(0.f, s), sw3[f * 20 + g], o);
                }
                kv = o;
            }
        }
        (f ? kv1 : kv0)[slot * NPTS + n] = kv;
        if (f == 0) kidx[slot * NPTS + n] = k;   // k=0 with kv=0 is harmless
    }

    // ---- device barrier: relaxed polls, ONE release + ONE acquire fence ----
    __syncthreads();   // compiler drains this wave's vmcnt before s_barrier
    if (t == 0) {
        __builtin_amdgcn_fence(__ATOMIC_RELEASE, "agent");          // single wbl2
        __hip_atomic_fetch_add(bar, 1u, __ATOMIC_RELAXED, __HIP_MEMORY_SCOPE_AGENT);
        while (__hip_atomic_load(bar, __ATOMIC_RELAXED, __HIP_MEMORY_SCOPE_AGENT)
               < (unsigned)NBLK)
            __builtin_amdgcn_s_sleep(8);                            // plain polls
        __builtin_amdgcn_fence(__ATOMIC_ACQUIRE, "agent");          // single inv
    }
    __syncthreads();

    // ---- phase 2: fields[b,n,f] = sigmoid(sum_j kv[f,n,j] * integ[b, kidx[n,j]])
    const int tid = bid * 512 + t;        // == b*2048 + n
    const int b = tid >> 11;
    const int n = tid & (NPTS - 1);
    float* srow = S;                      // this block's integ row (same b for all t)
    for (int i = t; i < KDIM; i += 512) srow[i] = integ[b * KDIM + i];
    __syncthreads();

    float a0 = 0.f, a1 = 0.f;
    #pragma unroll
    for (int j = 0; j < 16; ++j) {
        const int k = kidx[j * NPTS + n];
        const float w = srow[k];
        a0 = fmaf(kv0[j * NPTS + n], w, a0);
        a1 = fmaf(kv1[j * NPTS + n], w, a1);
    }
    out[tid] = make_float2(1.f / (1.f + __expf(-a0)),
                           1.f / (1.f + __expf(-a1)));
}

extern "C" void kernel_launch(void* const* d_in, const int* in_sizes, int n_in,
                              void* d_out, int out_size, void* d_ws, size_t ws_size,
                              hipStream_t stream) {
    const float* weights = (const float*)d_in[0];
    const float* grid    = (const float*)d_in[1];
    const float* ff_w1   = (const float*)d_in[2];
    const float* ff_b1   = (const float*)d_in[3];
    const float* ff_w2   = (const float*)d_in[4];
    const float* ff_b2   = (const float*)d_in[5];
    const float* ff_w3   = (const float*)d_in[6];
    const float* ff_b3   = (const float*)d_in[7];
    const float* k_w1    = (const float*)d_in[8];
    const float* k_b1    = (const float*)d_in[9];
    const float* k_w2    = (const float*)d_in[10];
    const float* k_b2    = (const float*)d_in[11];
    const float* k_w3    = (const float*)d_in[12];
    const float* k_b3    = (const float*)d_in[13];

    float* integ = (float*)d_ws;                 // 64*400
    float* kv0   = integ + 64 * KDIM;            // 16*2048
    float* kv1   = kv0 + 16 * NPTS;              // 16*2048
    int*   kidx  = (int*)(kv1 + 16 * NPTS);      // 16*2048
    unsigned int* bar = (unsigned int*)(kidx + 16 * NPTS);

    hipMemsetAsync(bar, 0, sizeof(unsigned int), stream);

    k_fused<<<NBLK, 512, 0, stream>>>(
        weights, grid, ff_w1, ff_b1, ff_w2, ff_b2, ff_w3, ff_b3,
        k_w1, k_b1, k_w2, k_b2, k_w3, k_b3,
        integ, kv0, kv1, kidx, bar, (float2*)d_out);
}